// Round 9
// baseline (245.181 us; speedup 1.0000x reference)
//
#include <hip/hip_runtime.h>

// region_pooling via scatter + dense GEMM + split-k partials.
// F: [B=8, HW=4096, C=1024] fp32 (H=W=64); pc: [B, M=32, P=512, 2]
// out[b,m,c] = sum_hw W[b][hw][m] * F[b][hw][c]; W = scattered bilinear
// weights pre-scaled by 1/P.
//
// v9: min-cycle build. 512-thr blocks (8 waves = 4 m-octets x 2 c-halves,
// F dedup'd across waves -> half the L1 traffic). FMA via v_pk_fma_f32
// (packed fp32, bit-identical): 16 pk-fma/step. W staged to LDS PRE-
// DUPLICATED {w,w} so pk operands come straight from broadcast ds_reads
// (no dup movs). F global->reg, SEG=16 batched double-buffer.

#define NB 8
#define NM 32
#define NP 512
#define NC 1024
#define NH 64
#define NHW 4096

#define KC    128                 // hw per k-chunk
#define NKC   (NHW / KC)          // 32 k-chunks
#define MT    8                   // m's per wave
#define CTILE 512                 // channels per block (2 halves x 256)
#define NCT   (NC / CTILE)        // 2 c-tiles
#define SEG   16                  // steps per segment
#define NSEG  (KC / SEG)          // 8 segments
#define FS4   (NC / 4)            // float4 stride per hw row

// ---- Phase 1: scatter bilinear weights into W[b][hw][m] (pre-zeroed) ----
__global__ __launch_bounds__(256) void scatter_w(
    const float* __restrict__ pc, float* __restrict__ W)
{
    int idx = blockIdx.x * 256 + threadIdx.x;   // [0, B*M*P)
    int bm  = idx >> 9;                         // b*NM + m
    int m   = bm & (NM - 1);
    int b   = bm >> 5;

    float2 c = ((const float2*)pc)[idx];
    float y = c.x * 63.0f;
    float x = c.y * 63.0f;
    float x0f = floorf(x), y0f = floorf(y);
    float wx = x - x0f, wy = y - y0f;
    int ix0 = min(max((int)x0f, 0), 63);
    int ix1 = min(ix0 + 1, 63);
    int iy0 = min(max((int)y0f, 0), 63);
    int iy1 = min(iy0 + 1, 63);
    float wx1 = 1.0f - wx, wy1 = 1.0f - wy;
    const float s = 1.0f / (float)NP;           // fold the mean here

    float* Wb = W + (size_t)b * (NHW * NM) + m;
    atomicAdd(Wb + ((iy0 * NH + ix0) * NM), wx1 * wy1 * s);
    atomicAdd(Wb + ((iy0 * NH + ix1) * NM), wx  * wy1 * s);
    atomicAdd(Wb + ((iy1 * NH + ix0) * NM), wx1 * wy  * s);
    atomicAdd(Wb + ((iy1 * NH + ix1) * NM), wx  * wy  * s);
}

// ---- Phase 2: P[kc][b][m][c] = sum_{hw in chunk kc} W[b][hw][m]*F[b][hw][c]
// Grid (NKC, NCT, NB) = (32, 2, 8) = 512 blocks x 512 thr (8 waves).
// Wave wid: mq = wid&3 (m-octet), ch = wid>>2 (channel half) -> waves read
// DISTINCT F (dedup). Lane owns 4 channels. ~185 VGPR -> 8 waves/CU.
__global__ __launch_bounds__(512) void wgemm(
    const float* __restrict__ W, const float* __restrict__ F,
    float* __restrict__ P)
{
    __shared__ float sW2[KC * NM * 2];          // 32 KB, {w,w} duplicated

    const int kc   = blockIdx.x;
    const int ct   = blockIdx.y;
    const int b    = blockIdx.z;
    const int tid  = threadIdx.x;
    const int wid  = tid >> 6;
    const int mq   = wid & 3;                   // m-octet
    const int ch   = wid >> 2;                  // channel half
    const int lane = tid & 63;
    const int hw0  = kc * KC;

    // stage W with duplication: src float4 i={w0,w1,w2,w3} ->
    // dst[2i]={w0,w0,w1,w1}, dst[2i+1]={w2,w2,w3,w3}
    {
        const float4* Wg = (const float4*)(W + ((size_t)b * NHW + hw0) * NM);
        float4* d = (float4*)sW2;
#pragma unroll
        for (int j = 0; j < 2; ++j) {
            int i = tid + 512 * j;
            float4 w = Wg[i];
            d[2 * i]     = make_float4(w.x, w.x, w.y, w.y);
            d[2 * i + 1] = make_float4(w.z, w.z, w.w, w.w);
        }
    }
    __syncthreads();                            // the only barrier

    const float4* __restrict__ Fb =
        (const float4*)(F + ((size_t)b * NHW + hw0) * NC
                        + ct * CTILE + ch * 256) + lane;

    float2 acc[MT][2];
#pragma unroll
    for (int m = 0; m < MT; ++m) {
        acc[m][0] = make_float2(0.f, 0.f);
        acc[m][1] = make_float2(0.f, 0.f);
    }

    // wave's duplicated-W base: row r occupies 64 floats; octet mq at +mq*16
    const float* sWq = sW2 + mq * 16;

    // one step on row r with f already in registers: 16 v_pk_fma_f32
#define STEP(r, f4v)                                                       \
    do {                                                                   \
        const float* wr_ = sWq + (r) * 64;                                 \
        float2 f01_ = make_float2((f4v).x, (f4v).y);                       \
        float2 f23_ = make_float2((f4v).z, (f4v).w);                       \
        _Pragma("unroll")                                                  \
        for (int m_ = 0; m_ < MT; ++m_) {                                  \
            float2 wd_ = *(const float2*)(wr_ + 2 * m_);  /* {w,w} */      \
            asm("v_pk_fma_f32 %0, %1, %2, %0"                              \
                : "+v"(acc[m_][0]) : "v"(wd_), "v"(f01_));                 \
            asm("v_pk_fma_f32 %0, %1, %2, %0"                              \
                : "+v"(acc[m_][1]) : "v"(wd_), "v"(f23_));                 \
        }                                                                  \
    } while (0)

    float4 bufA[SEG], bufB[SEG];

    // prologue: segment 0 -> bufA
#pragma unroll
    for (int j = 0; j < SEG; ++j) bufA[j] = Fb[j * FS4];

#pragma unroll
    for (int s = 0; s < NSEG; s += 2) {
        if (s + 1 < NSEG) {
#pragma unroll
            for (int j = 0; j < SEG; ++j)
                bufB[j] = Fb[((s + 1) * SEG + j) * FS4];
        }
#pragma unroll
        for (int j = 0; j < SEG; ++j) STEP(s * SEG + j, bufA[j]);

        if (s + 2 < NSEG) {
#pragma unroll
            for (int j = 0; j < SEG; ++j)
                bufA[j] = Fb[((s + 2) * SEG + j) * FS4];
        }
        if (s + 1 < NSEG) {
#pragma unroll
            for (int j = 0; j < SEG; ++j) STEP((s + 1) * SEG + j, bufB[j]);
        }
    }
#undef STEP

    // partials: P[((kc*NB + b)*NM + m)*NC + c]; coalesced float4 stores
    float* pb = P + (((size_t)kc * NB + b) * NM + mq * MT) * NC
              + ct * CTILE + ch * 256 + 4 * lane;
#pragma unroll
    for (int mm = 0; mm < MT; ++mm)
        *(float4*)(pb + (size_t)mm * NC) =
            make_float4(acc[mm][0].x, acc[mm][0].y,
                        acc[mm][1].x, acc[mm][1].y);
}

// ---- Phase 3: out = sum over the 32 k-chunk partials ----
__global__ __launch_bounds__(256) void reduce_p(
    const float* __restrict__ P, float* __restrict__ out)
{
    const int idx = blockIdx.x * 256 + threadIdx.x;   // [0, NB*NM*NC/4)
    const float4* p4 = (const float4*)P;
    const int stride = NB * NM * NC / 4;              // 65536
    float4 s = make_float4(0.f, 0.f, 0.f, 0.f);
#pragma unroll
    for (int kc = 0; kc < NKC; ++kc) {
        float4 v = p4[(size_t)kc * stride + idx];
        s.x += v.x; s.y += v.y; s.z += v.z; s.w += v.w;
    }
    ((float4*)out)[idx] = s;
}

// ---- Fallback (ws too small): direct gather ----
__global__ __launch_bounds__(256) void region_pool_direct(
    const float* __restrict__ fm, const float* __restrict__ pc,
    float* __restrict__ out)
{
    __shared__ int4   sIdx[NP];
    __shared__ float4 sWt[NP];
    const int bid = blockIdx.x;
    const int b   = bid >> 5;
    const int tid = threadIdx.x;
    const float2* pc2 = (const float2*)(pc + (size_t)bid * NP * 2);
    for (int p = tid; p < NP; p += 256) {
        float2 c = pc2[p];
        float y = c.x * 63.0f, x = c.y * 63.0f;
        float x0f = floorf(x), y0f = floorf(y);
        float wx = x - x0f, wy = y - y0f;
        int ix0 = min(max((int)x0f, 0), 63);
        int ix1 = min(ix0 + 1, 63);
        int iy0 = min(max((int)y0f, 0), 63);
        int iy1 = min(iy0 + 1, 63);
        sIdx[p] = make_int4((iy0 * NH + ix0) << 10, (iy0 * NH + ix1) << 10,
                            (iy1 * NH + ix0) << 10, (iy1 * NH + ix1) << 10);
        float wx1 = 1.0f - wx, wy1 = 1.0f - wy;
        sWt[p] = make_float4(wx1 * wy1, wx * wy1, wx1 * wy, wx * wy);
    }
    __syncthreads();
    const float* Fb = fm + (size_t)b * (NHW * NC) + tid * 4;
    float4 acc = make_float4(0.f, 0.f, 0.f, 0.f);
#pragma unroll 4
    for (int p = 0; p < NP; ++p) {
        int4 off = sIdx[p]; float4 w = sWt[p];
        float4 f00 = *(const float4*)(Fb + off.x);
        float4 f01 = *(const float4*)(Fb + off.y);
        float4 f10 = *(const float4*)(Fb + off.z);
        float4 f11 = *(const float4*)(Fb + off.w);
        acc.x = fmaf(w.x, f00.x, fmaf(w.y, f01.x, fmaf(w.z, f10.x, fmaf(w.w, f11.x, acc.x))));
        acc.y = fmaf(w.x, f00.y, fmaf(w.y, f01.y, fmaf(w.z, f10.y, fmaf(w.w, f11.y, acc.y))));
        acc.z = fmaf(w.x, f00.z, fmaf(w.y, f01.z, fmaf(w.z, f10.z, fmaf(w.w, f11.z, acc.z))));
        acc.w = fmaf(w.x, f00.w, fmaf(w.y, f01.w, fmaf(w.z, f10.w, fmaf(w.w, f11.w, acc.w))));
    }
    const float inv = 1.0f / (float)NP;
    ((float4*)(out + (size_t)bid * NC))[tid] =
        make_float4(acc.x * inv, acc.y * inv, acc.z * inv, acc.w * inv);
}

extern "C" void kernel_launch(void* const* d_in, const int* in_sizes, int n_in,
                              void* d_out, int out_size, void* d_ws, size_t ws_size,
                              hipStream_t stream) {
    const float* fm = (const float*)d_in[0];   // [8, 4096, 1024]
    const float* pc = (const float*)d_in[1];   // [8, 32, 512, 2]
    float* out = (float*)d_out;                // [8, 32, 1, 1024]

    const size_t wbytes = (size_t)NB * NHW * NM * sizeof(float);           // 4 MB
    const size_t pbytes = (size_t)NKC * NB * NM * NC * sizeof(float);      // 32 MB
    if (ws_size >= wbytes + pbytes) {
        float* W = (float*)d_ws;
        float* P = (float*)((char*)d_ws + wbytes);
        hipMemsetAsync(W, 0, wbytes, stream);
        scatter_w<<<(NB * NM * NP) / 256, 256, 0, stream>>>(pc, W);
        dim3 grid(NKC, NCT, NB);
        wgemm<<<grid, 512, 0, stream>>>(W, fm, P);
        reduce_p<<<(NB * NM * NC / 4) / 256, 256, 0, stream>>>(P, out);
    } else {
        region_pool_direct<<<NB * NM, 256, 0, stream>>>(fm, pc, out);
    }
}